// Round 5
// baseline (227.392 us; speedup 1.0000x reference)
//
#include <hip/hip_runtime.h>

// ProtoNet forward: per (b,p) pair 16x64 sinkhorn (30 it, eps=0.1) + FFN head.
// R5: ILP=2 — each wave runs TWO pairs (same molecule, adjacent p) as
// independent dependency chains to hide DS/rcp latency. Atom tiles + atom
// norms shared across the pair. ET-only packed state (no ER copy).
// lane = ig*16+jg; lane owns rows i=ig+4r, cols j=jg+16t.

typedef float v2f __attribute__((ext_vector_type(2)));
struct alignas(16) f4v { v2f lo, hi; };

constexpr int   LMAX_ = 64, D_ = 128, PCS_ = 16;
constexpr float EPS_   = 0.1f;
constexpr float LOG2E_ = 1.4426950408889634f;
constexpr float SCALE_ = LOG2E_ / EPS_;          // C -> base-2/eps units
constexpr float LN2_   = 0.6931471805599453f;

#if __has_builtin(__builtin_amdgcn_exp2f)
__device__ __forceinline__ float exp2_(float x) { return __builtin_amdgcn_exp2f(x); }
#else
__device__ __forceinline__ float exp2_(float x) { return exp2f(x); }
#endif
#if __has_builtin(__builtin_amdgcn_log2f)
__device__ __forceinline__ float log2_(float x) { return __builtin_amdgcn_log2f(x); }
#else
__device__ __forceinline__ float log2_(float x) { return log2f(x); }
#endif
#if __has_builtin(__builtin_amdgcn_rcpf)
__device__ __forceinline__ float rcp_(float x) { return __builtin_amdgcn_rcpf(x); }
#else
__device__ __forceinline__ float rcp_(float x) { return 1.0f / x; }
#endif

__device__ __forceinline__ v2f fma2(v2f a, v2f b, v2f c) {
  return __builtin_elementwise_fma(a, b, c);
}
__device__ __forceinline__ v2f splat(float x) { v2f r; r.x = x; r.y = x; return r; }
__device__ __forceinline__ v2f shxor2(v2f x, int m) {
  v2f r; r.x = __shfl_xor(x.x, m); r.y = __shfl_xor(x.y, m); return r;
}

__global__ __launch_bounds__(256, 4) void sink_fused(
    const float* __restrict__ atom_h,   // [512][64][128]
    const float* __restrict__ pc_X,     // [32][16][128]
    const int*   __restrict__ n_atoms,  // [512]
    float*       __restrict__ mol)      // [512][32] (ws)
{
  // [c4][row ^ (c4&7)] f4v layout: 32768 B. Reads conflict-free.
  __shared__ f4v Alds[2048];

  const int b    = blockIdx.x >> 2;                 // 4 blocks per molecule
  const int wave = threadIdx.x >> 6;
  const int p0   = (blockIdx.x & 3) * 8 + wave * 2; // two pairs: p0, p0+1
  const int lane = threadIdx.x & 63;
  const int ig   = lane >> 4;
  const int jg   = lane & 15;

  // ---- stage atom_h[b] into LDS (coalesced global reads) ----
  const f4v* Ag = reinterpret_cast<const f4v*>(atom_h + (size_t)b * (LMAX_ * D_));
  #pragma unroll
  for (int u = 0; u < 8; ++u) {
    int fidx = u * 256 + threadIdx.x;               // float4 index, 2048 total
    int row  = fidx >> 5;
    int c4   = fidx & 31;
    Alds[c4 * 64 + (row ^ (c4 & 7))] = Ag[row * 32 + c4];
  }
  __syncthreads();

  const int  n   = n_atoms[b];
  const f4v* XgA = reinterpret_cast<const f4v*>(pc_X) + (size_t)p0 * (PCS_ * D_ / 4);
  const f4v* XgB = XgA + (PCS_ * D_ / 4);

  // ---- cost tiles for both pairs, t-split to bound registers ----
  float Cbs[2][4][4], pn_s[2][4], an_s[4];
  #pragma unroll
  for (int half = 0; half < 2; ++half) {
    const int tb = half * 2;
    v2f acc[2][4][2], ana[2], pna[2][4];
    #pragma unroll
    for (int q = 0; q < 2; ++q)
      #pragma unroll
      for (int r = 0; r < 4; ++r) {
        acc[q][r][0] = splat(0.f); acc[q][r][1] = splat(0.f);
        if (half == 0) pna[q][r] = splat(0.f);
      }
    ana[0] = splat(0.f); ana[1] = splat(0.f);

    #pragma unroll 2
    for (int c = 0; c < 32; ++c) {
      const f4v* Ab = &Alds[c * 64 + (jg ^ (c & 7))];
      f4v a0 = Ab[tb * 16], a1 = Ab[tb * 16 + 16];
      ana[0] = fma2(a0.lo, a0.lo, ana[0]); ana[0] = fma2(a0.hi, a0.hi, ana[0]);
      ana[1] = fma2(a1.lo, a1.lo, ana[1]); ana[1] = fma2(a1.hi, a1.hi, ana[1]);
      #pragma unroll
      for (int r = 0; r < 4; ++r) {
        f4v xA = XgA[(ig + 4 * r) * 32 + c];
        f4v xB = XgB[(ig + 4 * r) * 32 + c];
        acc[0][r][0] = fma2(xA.lo, a0.lo, acc[0][r][0]);
        acc[0][r][0] = fma2(xA.hi, a0.hi, acc[0][r][0]);
        acc[0][r][1] = fma2(xA.lo, a1.lo, acc[0][r][1]);
        acc[0][r][1] = fma2(xA.hi, a1.hi, acc[0][r][1]);
        acc[1][r][0] = fma2(xB.lo, a0.lo, acc[1][r][0]);
        acc[1][r][0] = fma2(xB.hi, a0.hi, acc[1][r][0]);
        acc[1][r][1] = fma2(xB.lo, a1.lo, acc[1][r][1]);
        acc[1][r][1] = fma2(xB.hi, a1.hi, acc[1][r][1]);
        if (half == 0) {
          pna[0][r] = fma2(xA.lo, xA.lo, pna[0][r]);
          pna[0][r] = fma2(xA.hi, xA.hi, pna[0][r]);
          pna[1][r] = fma2(xB.lo, xB.lo, pna[1][r]);
          pna[1][r] = fma2(xB.hi, xB.hi, pna[1][r]);
        }
      }
    }
    if (half == 0) {
      #pragma unroll
      for (int q = 0; q < 2; ++q)
        #pragma unroll
        for (int r = 0; r < 4; ++r)
          pn_s[q][r] = pna[q][r].x + pna[q][r].y;
    }
    an_s[tb]     = ana[0].x + ana[0].y;
    an_s[tb + 1] = ana[1].x + ana[1].y;
    #pragma unroll
    for (int q = 0; q < 2; ++q)
      #pragma unroll
      for (int r = 0; r < 4; ++r)
        #pragma unroll
        for (int h = 0; h < 2; ++h)
          Cbs[q][r][tb + h] = fmaf(-2.0f, acc[q][r][h].x + acc[q][r][h].y,
                                   pn_s[q][r] + an_s[tb + h]) * SCALE_;
  }

  // ---- phase 1: 2 log-domain iterations (base-2 units), both pairs ----
  float lb2[4], F[2][4], G[2][4], bm[4];
  const float lbv = -log2_((float)n);
  const float bn  = 1.0f / (float)n;
  #pragma unroll
  for (int t = 0; t < 4; ++t) {
    const int j  = jg + 16 * t;
    const bool v = (j < n);
    lb2[t] = v ? lbv : -1.4426950e9f;        // log2e * NEG
    bm[t]  = v ? bn : 0.0f;
    G[0][t] = v ? 0.0f : -1e9f;
    G[1][t] = G[0][t];
  }

  #pragma unroll 1
  for (int it = 0; it < 2; ++it) {
    #pragma unroll
    for (int q = 0; q < 2; ++q) {
      #pragma unroll
      for (int r = 0; r < 4; ++r) {
        float x0 = G[q][0] - Cbs[q][r][0], x1 = G[q][1] - Cbs[q][r][1];
        float x2 = G[q][2] - Cbs[q][r][2], x3 = G[q][3] - Cbs[q][r][3];
        float m = fmaxf(fmaxf(x0, x1), fmaxf(x2, x3));
        m = fmaxf(m, __shfl_xor(m, 1));
        m = fmaxf(m, __shfl_xor(m, 2));
        m = fmaxf(m, __shfl_xor(m, 4));
        m = fmaxf(m, __shfl_xor(m, 8));
        float s = exp2_(x0 - m) + exp2_(x1 - m) + exp2_(x2 - m) + exp2_(x3 - m);
        s += __shfl_xor(s, 1);
        s += __shfl_xor(s, 2);
        s += __shfl_xor(s, 4);
        s += __shfl_xor(s, 8);
        F[q][r] = -4.0f - (m + log2_(s));
      }
      #pragma unroll
      for (int t = 0; t < 4; ++t) {
        float y0 = F[q][0] - Cbs[q][0][t], y1 = F[q][1] - Cbs[q][1][t];
        float y2 = F[q][2] - Cbs[q][2][t], y3 = F[q][3] - Cbs[q][3][t];
        float m = fmaxf(fmaxf(y0, y1), fmaxf(y2, y3));
        m = fmaxf(m, __shfl_xor(m, 16));
        m = fmaxf(m, __shfl_xor(m, 32));
        float s = exp2_(y0 - m) + exp2_(y1 - m) + exp2_(y2 - m) + exp2_(y3 - m);
        s += __shfl_xor(s, 16);
        s += __shfl_xor(s, 32);
        G[q][t] = lb2[t] - (m + log2_(s));
      }
    }
  }

  // ---- phase 2: 28 multiplicative iterations on ET = 2^(F+G-Cb) ----
  // ET[q][r][h] = (E[r][2h], E[r][2h+1]); padded cols exactly 0.
  v2f ET[2][4][2];
  #pragma unroll
  for (int q = 0; q < 2; ++q)
    #pragma unroll
    for (int r = 0; r < 4; ++r)
      #pragma unroll
      for (int h = 0; h < 2; ++h) {
        v2f e;
        e.x = exp2_(F[q][r] + G[q][2 * h]     - Cbs[q][r][2 * h]);
        e.y = exp2_(F[q][r] + G[q][2 * h + 1] - Cbs[q][r][2 * h + 1]);
        ET[q][r][h] = e;
      }

  v2f bm2[2];
  bm2[0].x = bm[0]; bm2[0].y = bm[1];
  bm2[1].x = bm[2]; bm2[1].y = bm[3];
  const v2f tiny = splat(1e-30f);

  float u[2][4];
  v2f   vv[2][2];

  // one sinkhorn mult-iteration for both pairs (independent chains)
  auto iter = [&](bool first) {
    #pragma unroll
    for (int q = 0; q < 2; ++q) {
      float s[4];
      #pragma unroll
      for (int r = 0; r < 4; ++r) {
        v2f z;
        if (first) {
          z = ET[q][r][0] + ET[q][r][1];
        } else {
          z = ET[q][r][0] * vv[q][0];
          z = fma2(ET[q][r][1], vv[q][1], z);
        }
        s[r] = z.x + z.y;
      }
      v2f w01; w01.x = s[0]; w01.y = s[1];
      v2f w23; w23.x = s[2]; w23.y = s[3];
      w01 = w01 + shxor2(w01, 1);  w23 = w23 + shxor2(w23, 1);
      w01 = w01 + shxor2(w01, 2);  w23 = w23 + shxor2(w23, 2);
      w01 = w01 + shxor2(w01, 4);  w23 = w23 + shxor2(w23, 4);
      w01 = w01 + shxor2(w01, 8);  w23 = w23 + shxor2(w23, 8);
      u[q][0] = 0.0625f * rcp_(w01.x); u[q][1] = 0.0625f * rcp_(w01.y);
      u[q][2] = 0.0625f * rcp_(w23.x); u[q][3] = 0.0625f * rcp_(w23.y);

      v2f T0 = ET[q][0][0] * splat(u[q][0]);
      v2f T1 = ET[q][0][1] * splat(u[q][0]);
      T0 = fma2(ET[q][1][0], splat(u[q][1]), T0);
      T1 = fma2(ET[q][1][1], splat(u[q][1]), T1);
      T0 = fma2(ET[q][2][0], splat(u[q][2]), T0);
      T1 = fma2(ET[q][2][1], splat(u[q][2]), T1);
      T0 = fma2(ET[q][3][0], splat(u[q][3]), T0);
      T1 = fma2(ET[q][3][1], splat(u[q][3]), T1);
      T0 = T0 + shxor2(T0, 16);  T1 = T1 + shxor2(T1, 16);
      T0 = T0 + shxor2(T0, 32);  T1 = T1 + shxor2(T1, 32);
      T0 = T0 + tiny;            T1 = T1 + tiny;
      v2f r0; r0.x = rcp_(T0.x); r0.y = rcp_(T0.y);
      v2f r1; r1.x = rcp_(T1.x); r1.y = rcp_(T1.y);
      vv[q][0] = bm2[0] * r0;
      vv[q][1] = bm2[1] * r1;
    }
  };

  #pragma unroll 1
  for (int blk = 0; blk < 4; ++blk) {            // 4 blocks x 7 iters = 28
    iter(true);
    #pragma unroll 1
    for (int it = 1; it < 7; ++it) iter(false);
    // re-absorb u,v into ET (next block's first iter assumes v==1)
    #pragma unroll
    for (int q = 0; q < 2; ++q)
      #pragma unroll
      for (int r = 0; r < 4; ++r) {
        ET[q][r][0] = ET[q][r][0] * (splat(u[q][r]) * vv[q][0]);
        ET[q][r][1] = ET[q][r][1] * (splat(u[q][r]) * vv[q][1]);
      }
  }

  // ---- dist: ET == P. d = sum P*Cb; pack both pairs for the butterfly ----
  float dq[2];
  #pragma unroll
  for (int q = 0; q < 2; ++q) {
    v2f d2 = splat(0.f);
    #pragma unroll
    for (int r = 0; r < 4; ++r) {
      v2f cb0; cb0.x = Cbs[q][r][0]; cb0.y = Cbs[q][r][1];
      v2f cb1; cb1.x = Cbs[q][r][2]; cb1.y = Cbs[q][r][3];
      d2 = fma2(ET[q][r][0], cb0, d2);
      d2 = fma2(ET[q][r][1], cb1, d2);
    }
    dq[q] = d2.x + d2.y;
  }
  v2f dd; dd.x = dq[0]; dd.y = dq[1];
  dd = dd + shxor2(dd, 1);
  dd = dd + shxor2(dd, 2);
  dd = dd + shxor2(dd, 4);
  dd = dd + shxor2(dd, 8);
  dd = dd + shxor2(dd, 16);
  dd = dd + shxor2(dd, 32);

  if (lane == 0) {
    const float k = -(EPS_ * LN2_ * 16.0f / 100.0f) * (float)n;
    mol[b * 32 + p0]     = k * dd.x;
    mol[b * 32 + p0 + 1] = k * dd.y;
  }
}

__global__ __launch_bounds__(256) void ffn_head(
    const float* __restrict__ mol,  // [512][32]
    const float* __restrict__ W1,   // [32][256]
    const float* __restrict__ b1,   // [256]
    const float* __restrict__ W2,   // [256][1]
    const float* __restrict__ b2,   // [1]
    float*       __restrict__ out)  // [512]
{
  const int b = blockIdx.x;
  const int j = threadIdx.x;
  float m[32];
  #pragma unroll
  for (int k = 0; k < 32; ++k) m[k] = mol[b * 32 + k];
  float acc = b1[j];
  #pragma unroll
  for (int k = 0; k < 32; ++k) acc = fmaf(m[k], W1[k * 256 + j], acc);
  float v = fmaxf(acc, 0.0f) * W2[j];
  #pragma unroll
  for (int mask = 1; mask < 64; mask <<= 1) v += __shfl_xor(v, mask);
  __shared__ float red[4];
  if ((threadIdx.x & 63) == 0) red[threadIdx.x >> 6] = v;
  __syncthreads();
  if (threadIdx.x == 0) out[b] = red[0] + red[1] + red[2] + red[3] + b2[0];
}

extern "C" void kernel_launch(void* const* d_in, const int* in_sizes, int n_in,
                              void* d_out, int out_size, void* d_ws, size_t ws_size,
                              hipStream_t stream) {
  const float* atom_h = (const float*)d_in[0];
  const float* pc_X   = (const float*)d_in[1];
  const float* W1     = (const float*)d_in[2];
  const float* b1     = (const float*)d_in[3];
  const float* W2     = (const float*)d_in[4];
  const float* b2     = (const float*)d_in[5];
  const int*   n_at   = (const int*)d_in[6];

  float* mol = (float*)d_ws;           // 512*32*4 = 64 KB scratch
  float* out = (float*)d_out;          // [512] fp32

  sink_fused<<<2048, 256, 0, stream>>>(atom_h, pc_X, n_at, mol);
  ffn_head<<<512, 256, 0, stream>>>(mol, W1, b1, W2, b2, out);
}